// Round 3
// baseline (453.096 us; speedup 1.0000x reference)
//
#include <hip/hip_runtime.h>

// Causal self-attention. fp32 in/out, bf16 MFMA compute inside.
// R10: QKV GEMM reshaped to BM=256 x BN=384 x BK=32, grid 16x16 = 256 blocks
// = exactly ONE dispatch round (R9 was 384 blocks -> 2 rounds, 25% idle).
// Triple-buffered LDS (3 x 40KB = 120KB, 1 block/CU): tile t stages tile t+2
// (A in P0, B in P1) into buf (t+2)%3 whose last reader was t-1; boundary
// vmcnt(5) keeps 5 loads in flight -> staging covered by ~2 full tiles.
// 2 phases/tile, 24 MFMA/phase (vs 16) -> barriers/tile 8 -> 4.
// T2 swizzle unchanged from R9 (granule g at row r stored at g^((r>>1)&3),
// LDS linear, inverse perm on global source, same perm on read offset;
// verified 0 conflicts in R9). Per-wave C = 128x96: acc 192 VGPR (tight).
// Flash attn + out-GEMM (m97 128^2) unchanged.
// MFMA 16x16x32 bf16 layouts (guide m89/m91):
//   A[m=lane&15][k=quad*8+j], B[k=quad*8+j][n=lane&15], C/D: row=quad*4+r, col=lane&15

typedef unsigned short ushort;
typedef __attribute__((ext_vector_type(8))) short short8;
typedef __attribute__((ext_vector_type(4))) float floatx4;

#define T_SEQ 2048
#define NQKV  6144
#define DMODEL 2048
#define HDIM  128
#define NEG_BIG (-3.0e38f)

#define WAITVM(n) asm volatile("s_waitcnt vmcnt(" #n ")" ::: "memory")
#define WAITLGKM0 asm volatile("s_waitcnt lgkmcnt(0)" ::: "memory")

__device__ __forceinline__ ushort f2bf(float f) {
  unsigned u = __float_as_uint(f);
  u += 0x7fffu + ((u >> 16) & 1u);   // RNE
  return (ushort)(u >> 16);
}
__device__ __forceinline__ void stout(ushort* p, float v) { *p = f2bf(v); }
__device__ __forceinline__ void stout(float* p, float v)  { *p = v; }

__device__ __forceinline__ void gload_lds16(const ushort* g, ushort* l) {
  __builtin_amdgcn_global_load_lds(
      (const __attribute__((address_space(1))) void*)g,
      (__attribute__((address_space(3))) void*)l,
      16, 0, 0);
}

// ---- fp32 [R x C] (row stride ld_in) -> dense bf16 [R x C] ----
__global__ void cvt2d(const float* __restrict__ in, ushort* __restrict__ out,
                      int R, int C, int ld_in) {
  int idx = blockIdx.x * blockDim.x + threadIdx.x;
  int c4 = C >> 2;
  if (idx >= R * c4) return;
  int r = idx / c4, c = (idx - r * c4) * 4;
  float4 v = *(const float4*)(in + (size_t)r * ld_in + c);
  ushort4 o;
  o.x = f2bf(v.x); o.y = f2bf(v.y); o.z = f2bf(v.z); o.w = f2bf(v.w);
  *(ushort4*)(out + (size_t)r * C + c) = o;
}

// ---- fp32 in[R][C] (row stride ld_in) -> bf16 out[C][R] dense ----
__global__ void cvt2dT(const float* __restrict__ in, ushort* __restrict__ out,
                       int R, int C, int ld_in) {
  __shared__ float tile[32][33];
  int c0 = blockIdx.x * 32, r0 = blockIdx.y * 32;
  int tx = threadIdx.x, ty = threadIdx.y;  // 32 x 8
#pragma unroll
  for (int q = 0; q < 4; q++)
    tile[ty + q * 8][tx] = in[(size_t)(r0 + ty + q * 8) * ld_in + c0 + tx];
  __syncthreads();
#pragma unroll
  for (int q = 0; q < 4; q++)
    out[(size_t)(c0 + ty + q * 8) * R + r0 + tx] = f2bf(tile[tx][ty + q * 8]);
}

// ---- C[M,N] = A[M,K] @ Bt[N,K]^T, bf16 in, OutT out (m97 structure) ----
template <typename OutT>
__global__ void gemm_bt(
    const ushort* __restrict__ A, const ushort* __restrict__ Bt,
    OutT* __restrict__ C, int M, int N, int K, int ldc) {
  __shared__ ushort sA[128 * 32];
  __shared__ ushort sB[128 * 32];
  const int tid = threadIdx.x;
  const int w = tid >> 6, l = tid & 63;
  const int quad = l >> 4, l16 = l & 15;
  const int row0 = blockIdx.x * 128, col0 = blockIdx.y * 128;
  const int wm = (w >> 1) * 64, wn = (w & 1) * 64;

  floatx4 acc[4][4];
  const floatx4 zero = {0.f, 0.f, 0.f, 0.f};
#pragma unroll
  for (int i = 0; i < 4; i++)
#pragma unroll
    for (int j = 0; j < 4; j++) acc[i][j] = zero;

  const int srow = w * 16 + (l >> 2);
  const int scol = (l & 3) * 8;
  const ushort* gA = A + (size_t)(row0 + srow) * K + scol;
  const ushort* gB = Bt + (size_t)(col0 + srow) * K + scol;
  ushort* lA = &sA[(w * 16) * 32];
  ushort* lB = &sB[(w * 16) * 32];

  for (int k0 = 0; k0 < K; k0 += 32) {
    __syncthreads();
    gload_lds16(gA + k0, lA);
    gload_lds16(gA + k0 + (size_t)64 * K, lA + 64 * 32);
    gload_lds16(gB + k0, lB);
    gload_lds16(gB + k0 + (size_t)64 * K, lB + 64 * 32);
    __syncthreads();
    short8 af[4], bfr[4];
#pragma unroll
    for (int i = 0; i < 4; i++)
      af[i] = *(const short8*)&sA[(wm + i * 16 + l16) * 32 + quad * 8];
#pragma unroll
    for (int j = 0; j < 4; j++)
      bfr[j] = *(const short8*)&sB[(wn + j * 16 + l16) * 32 + quad * 8];
#pragma unroll
    for (int i = 0; i < 4; i++)
#pragma unroll
      for (int j = 0; j < 4; j++)
        acc[i][j] = __builtin_amdgcn_mfma_f32_16x16x32_bf16(af[i], bfr[j], acc[i][j], 0, 0, 0);
  }

#pragma unroll
  for (int i = 0; i < 4; i++)
#pragma unroll
    for (int j = 0; j < 4; j++) {
      int r0 = row0 + wm + i * 16 + quad * 4;
      int c = col0 + wn + j * 16 + l16;
#pragma unroll
      for (int r = 0; r < 4; r++)
        stout(&C[(size_t)(r0 + r) * ldc + c], acc[i][j][r]);
    }
}

// ---- QKV GEMM: C[M,N] = A[M,K] @ Bt[N,K]^T, BM=256 BN=384 BK=32 ----
// 512 threads = 8 waves (2M x 4N); per-wave C = 128x96 (8 m-frags x 6 n-frags).
// LDS: sA[3][256*32] + sB[3][384*32] = 120KB triple-buffered.
// Swizzle (rule #21): granule g of row r at physical g^((r>>1)&3); LDS dest of
// global_load_lds stays linear; global source pre-permuted (lane l loads
// granule (l&3)^((l>>3)&3) of row l>>2 in each 16-row chunk); reads use
// quad^((l16>>1)&3). All chunk/frag row bases are multiples of 16 -> formulas
// row-base-independent. 64 lanes hit all 32 banks exactly 2x -> conflict-free.
// Tile t: P0 reads bfr[6]+af[0..3], stages A(t+2); P1 reads af[4..7], stages
// B(t+2). Boundary vmcnt(5) = t+2's loads in flight, t+1 landed.
template <typename OutT>
__global__ __launch_bounds__(512, 2) void gemm_qkv(
    const ushort* __restrict__ A, const ushort* __restrict__ Bt,
    OutT* __restrict__ C, int M, int N, int K, int ldc) {
  __shared__ ushort sA[3][256 * 32];
  __shared__ ushort sB[3][384 * 32];
  const int tid = threadIdx.x;
  const int wid = tid >> 6, l = tid & 63;
  const int quad = l >> 4, l16 = l & 15;
  const int wr = wid >> 2, wc = wid & 3;   // 2M x 4N
  const int row0 = blockIdx.x * 256, col0 = blockIdx.y * 384;
  const int NT = K >> 5;  // BK=32

  floatx4 acc[8][6];
  const floatx4 zero = {0.f, 0.f, 0.f, 0.f};
#pragma unroll
  for (int i = 0; i < 8; i++)
#pragma unroll
    for (int j = 0; j < 6; j++) acc[i][j] = zero;

  // stage source: lane l -> row chunkbase+(l>>2), granule (l&3)^((l>>3)&3)
  const int sgr = ((l & 3) ^ ((l >> 3) & 3)) * 8;
  const ushort* gA = A + (size_t)(row0 + wid * 32 + (l >> 2)) * K + sgr;
  const ushort* gB = Bt + (size_t)(col0 + wid * 48 + (l >> 2)) * K + sgr;

  auto stageA = [&](int tt) {   // 2 loads: wave wid covers rows wid*32..+31
    ushort* dst = &sA[tt % 3][(wid * 32) * 32];
    const ushort* g = gA + tt * 32;
    gload_lds16(g, dst);
    gload_lds16(g + (size_t)16 * K, dst + 16 * 32);
  };
  auto stageB = [&](int tt) {   // 3 loads: wave wid covers rows wid*48..+47
    ushort* dst = &sB[tt % 3][(wid * 48) * 32];
    const ushort* g = gB + tt * 32;
    gload_lds16(g, dst);
    gload_lds16(g + (size_t)16 * K, dst + 16 * 32);
    gload_lds16(g + (size_t)32 * K, dst + 32 * 32);
  };

  // read-side swizzled granule offset (frag row mod 16 == l16)
  const int gsw = (quad ^ ((l16 >> 1) & 3)) * 8;

  // prologue: stage t0 + t1; vmcnt(5) -> t0 landed, t1's 5 in flight
  stageA(0); stageB(0);
  if (NT > 1) {
    stageA(1); stageB(1);
    WAITVM(5);
  } else {
    WAITVM(0);
  }
  __builtin_amdgcn_s_barrier();

  for (int t = 0; t < NT; ++t) {
    const int b = t % 3;
    short8 af[4], bfr[6];
    // ---- P0: C-rows 0..63 of wave (m-frags 0..3) ----
#pragma unroll
    for (int j = 0; j < 6; j++)
      bfr[j] = *(const short8*)&sB[b][(wc * 96 + j * 16 + l16) * 32 + gsw];
#pragma unroll
    for (int i = 0; i < 4; i++)
      af[i] = *(const short8*)&sA[b][(wr * 128 + i * 16 + l16) * 32 + gsw];
    if (t + 2 < NT) stageA(t + 2);
    __builtin_amdgcn_s_barrier();
    WAITLGKM0;
    __builtin_amdgcn_s_setprio(1);
#pragma unroll
    for (int i = 0; i < 4; i++)
#pragma unroll
      for (int j = 0; j < 6; j++)
        acc[i][j] = __builtin_amdgcn_mfma_f32_16x16x32_bf16(af[i], bfr[j], acc[i][j], 0, 0, 0);
    __builtin_amdgcn_s_setprio(0);
    __builtin_amdgcn_s_barrier();
    // ---- P1: C-rows 64..127 (m-frags 4..7); bfr reused ----
#pragma unroll
    for (int i = 0; i < 4; i++)
      af[i] = *(const short8*)&sA[b][(wr * 128 + (4 + i) * 16 + l16) * 32 + gsw];
    if (t + 2 < NT) stageB(t + 2);
    __builtin_amdgcn_s_barrier();
    WAITLGKM0;
    __builtin_amdgcn_s_setprio(1);
#pragma unroll
    for (int i = 0; i < 4; i++)
#pragma unroll
      for (int j = 0; j < 6; j++)
        acc[4 + i][j] = __builtin_amdgcn_mfma_f32_16x16x32_bf16(af[i], bfr[j], acc[4 + i][j], 0, 0, 0);
    __builtin_amdgcn_s_setprio(0);
    if (t < NT - 2) { WAITVM(5); } else if (t == NT - 2) { WAITVM(0); }
    __builtin_amdgcn_s_barrier();
  }

#pragma unroll
  for (int mi = 0; mi < 8; mi++)
#pragma unroll
    for (int j = 0; j < 6; j++) {
      int r0 = row0 + wr * 128 + mi * 16 + quad * 4;
      int c = col0 + wc * 96 + j * 16 + l16;
#pragma unroll
      for (int r = 0; r < 4; r++)
        stout(&C[(size_t)(r0 + r) * ldc + c], acc[mi][j][r]);
    }
}

// ---- flash attention (causal): one 64-row q-tile per block; grid (bh, qtOrd) ----
// sK: 2 buffers, 16 groups each; group = 4 rows x 128 ushort + 16-ushort pad
// (528 ushort stride). DMA writes one group per instruction (1024B contig);
// the pad staggers groups by 8 banks -> K-fragment b128 reads are 4-way.
__global__ __launch_bounds__(256, 2) void flash_attn(
    const ushort* __restrict__ qkv, ushort* __restrict__ attn) {
  __shared__ ushort sK[2][16 * 528];
  __shared__ ushort sVt[128 * 72];   // swizzled [hd][t]
  __shared__ ushort sP[4 * 16 * 72]; // per-wave P, stride 72

  const int tid = threadIdx.x;
  const int w = tid >> 6, l = tid & 63;
  const int quad = l >> 4, l16 = l & 15;
  const int bh = blockIdx.x;            // bh-major: same-bh blocks share an XCD
  const int qt = 31 - (int)blockIdx.y;  // biggest blocks dispatch first
  const int b = bh >> 4, h = bh & 15;
  const size_t rowbase = (size_t)b * T_SEQ;

  short8 qf[4];
  {
    const ushort* qp = qkv + (rowbase + qt * 64 + w * 16 + l16) * NQKV + h * HDIM + quad * 8;
#pragma unroll
    for (int s = 0; s < 4; s++) qf[s] = *(const short8*)(qp + s * 32);
  }
  floatx4 o[8];
  const floatx4 zero = {0.f, 0.f, 0.f, 0.f};
#pragma unroll
  for (int n = 0; n < 8; n++) o[n] = zero;
  float m_i[4], l_i[4];
#pragma unroll
  for (int r = 0; r < 4; r++) { m_i[r] = NEG_BIG; l_i[r] = 0.f; }

  // K DMA: instr c stages group w*4+c (rows w*16+c*4..+3);
  // lane l -> row +(l>>4), cols (l&15)*8..+7.
  const ushort* gK = qkv + (rowbase + w * 16 + (l >> 4)) * NQKV + 2048 + h * HDIM + (l & 15) * 8;
  auto issueK = [&](int kt, int buf) {
#pragma unroll
    for (int c = 0; c < 4; c++)
      gload_lds16(gK + (size_t)(kt * 64 + c * 4) * NQKV, &sK[buf][(w * 4 + c) * 528]);
  };
  // V: thread covers hd v_hd0..+7, t pair v_t0 (+32c)
  const int v_hd0 = (tid & 15) * 8;
  const int v_t0 = 2 * (tid >> 4);
  const ushort* gV = qkv + rowbase * NQKV + 4096 + h * HDIM + v_hd0;
  short8 vcur[4], vnxt[4];  // [0..1]=row t0 (c=0,1), [2..3]=row t0+1
  auto loadV = [&](int kt, short8* dst) {
#pragma unroll
    for (int c = 0; c < 2; c++) {
      const ushort* g = gV + (size_t)(kt * 64 + v_t0 + 32 * c) * NQKV;
      dst[c] = *(const short8*)g;
      dst[2 + c] = *(const short8*)(g + NQKV);
    }
  };

  ushort* myP = &sP[w * 16 * 72];
  const float scale = 0.08838834764831845f;  // 1/sqrt(128)

  auto attn_step = [&](bool diag, int buf) {
    floatx4 S[4];
#pragma unroll
    for (int j = 0; j < 4; j++) S[j] = zero;
#pragma unroll
    for (int s = 0; s < 4; s++)
#pragma unroll
      for (int j = 0; j < 4; j++) {
        int row = j * 16 + l16;
        short8 kf = *(const short8*)&sK[buf][(row >> 2) * 528 + (row & 3) * 128 + s * 32 + quad * 8];
        S[j] = __builtin_amdgcn_mfma_f32_16x16x32_bf16(qf[s], kf, S[j], 0, 0, 0);
      }
#pragma unroll
    for (int j = 0; j < 4; j++)
#pragma unroll
      for (int r = 0; r < 4; r++) {
        float v = S[j][r] * scale;
        if (diag && (j * 16 + l16 > w * 16 + quad * 4 + r)) v = NEG_BIG;
        S[j][r] = v;
      }
    float alpha[4];
#pragma unroll
    for (int r = 0; r < 4; r++) {
      float v = fmaxf(fmaxf(S[0][r], S[1][r]), fmaxf(S[2][r], S[3][r]));
      v = fmaxf(v, __shfl_xor(v, 1, 16));
      v = fmaxf(v, __shfl_xor(v, 2, 16));
      v = fmaxf(v, __shfl_xor(v, 4, 16));
      v = fmaxf(v, __shfl_xor(v, 8, 16));
      float mn = fmaxf(m_i[r], v);
      alpha[r] = __expf(m_i[r] - mn);
      m_i[r] = mn;
    }
#pragma unroll
    for (int j = 0; j < 4; j++)
#pragma unroll
      for (int r = 0; r < 4; r++) S[j][r] = __expf(S[j][r] - m_i[r]);
#pragma unroll
    for (int r = 0; r < 4; r++)
      l_i[r] = l_i[r] * alpha[r] + S[0][r] + S[1][r] + S[2][r] + S[3][r];
#pragma unroll
    for (int n = 0; n < 8; n++)
#pragma unroll
      for (int r = 0; r < 4; r++) o[n][r] *= alpha[r];
#pragma unroll
    for (int j = 0; j < 4; j++)
#pragma unroll
      for (int r = 0; r < 4; r++)
        myP[(quad * 4 + r) * 72 + j * 16 + l16] = f2bf(S[j][r]);
#pragma unroll
    for (int s = 0; s < 2; s++) {
      short8 pf = *(const short8*)&myP[l16 * 72 + s * 32 + quad * 8];
#pragma unroll
      for (int n = 0; n < 8; n++) {
        int hd = n * 16 + l16;
        short8 vf = *(const short8*)&sVt[hd * 72 + 8 * ((s * 4 + quad) ^ ((hd >> 3) & 7))];
        o[n] = __builtin_amdgcn_mfma_f32_16x16x32_bf16(pf, vf, o[n], 0, 0, 0);
      }
    }
  };

  issueK(0, 0);
  loadV(0, vcur);
  for (int kt = 0; kt <= qt; kt++) {
    const int buf = kt & 1;
    __syncthreads();   // drains this buf's K DMA (vmcnt0) + prev iter LDS reads
    // V^T staging (swizzled: write banks 2-way, reads b128 16B-aligned)
#pragma unroll
    for (int c = 0; c < 2; c++) {
      int tw = (v_t0 >> 1) + 16 * c;
#pragma unroll
      for (int j = 0; j < 8; j++) {
        int hd = v_hd0 + j;
        int phys = hd * 72 + 2 * (tw & 3) + 8 * ((tw >> 2) ^ ((hd >> 3) & 7));
        unsigned pv = ((unsigned)(ushort)vcur[c][j]) | (((unsigned)(ushort)vcur[2 + c][j]) << 16);
        *(unsigned*)&sVt[phys] = pv;
      }
    }
    __syncthreads();
    if (kt < qt) {     // prefetch next tile during this tile's compute
      issueK(kt + 1, buf ^ 1);
      loadV(kt + 1, vnxt);
    }
    attn_step(kt == qt, buf);
    if (kt < qt) {
#pragma unroll
      for (int c = 0; c < 4; c++) vcur[c] = vnxt[c];
    }
  }

  // epilogue: 1/l and store
#pragma unroll
  for (int r = 0; r < 4; r++) {
    float v = l_i[r];
    v += __shfl_xor(v, 1, 16);
    v += __shfl_xor(v, 2, 16);
    v += __shfl_xor(v, 4, 16);
    v += __shfl_xor(v, 8, 16);
    l_i[r] = 1.0f / v;
  }
#pragma unroll
  for (int n = 0; n < 8; n++) {
    int col = h * HDIM + n * 16 + l16;
#pragma unroll
    for (int r = 0; r < 4; r++) {
      int row = qt * 64 + w * 16 + quad * 4 + r;
      attn[(rowbase + row) * DMODEL + col] = f2bf(o[n][r] * l_i[r]);
    }
  }
}

extern "C" void kernel_launch(void* const* d_in, const int* in_sizes, int n_in,
                              void* d_out, int out_size, void* d_ws, size_t ws_size,
                              hipStream_t stream) {
  const float* xf    = (const float*)d_in[0];   // [4096, 2048] fp32
  const float* Wqkvf = (const float*)d_in[1];   // [2048, 6144] fp32
  const float* Woutf = (const float*)d_in[2];   // [2048, 2048] fp32
  float* outf = (float*)d_out;                  // [4096, 2048] fp32
  char* ws = (char*)d_ws;

  const size_t SZ_QKV  = (size_t)4096 * 6144 * 2;  // 50.33 MB
  const size_t SZ_ATTN = (size_t)4096 * 2048 * 2;  // 16.78 MB
  const size_t SZ_WQT  = (size_t)6144 * 2048 * 2;  // 25.17 MB

  ushort* xb = (ushort*)d_out;  // bf16 x in d_out scratch (dead before final write)
  cvt2d<<<8192, 256, 0, stream>>>(xf, xb, 4096, 2048, 2048);

  if (ws_size >= SZ_QKV + SZ_ATTN + SZ_WQT) {
    // Tier A: un-sliced QKV gemm (256x384 1-round), attn in ws, final gemm to d_out.
    ushort* qkv   = (ushort*)ws;
    ushort* attnb = (ushort*)(ws + SZ_QKV);
    ushort* WT    = (ushort*)(ws + SZ_QKV + SZ_ATTN);
    cvt2dT<<<dim3(192, 64), dim3(32, 8), 0, stream>>>(Wqkvf, WT, 2048, 6144, NQKV);
    gemm_qkv<ushort><<<dim3(16, 16), 512, 0, stream>>>(xb, WT, qkv, 4096, 6144, 2048, NQKV);
    flash_attn<<<dim3(32, 32), 256, 0, stream>>>(qkv, attnb);
    cvt2dT<<<dim3(64, 64), dim3(32, 8), 0, stream>>>(Woutf, WT, 2048, 2048, 2048);
    gemm_bt<float><<<dim3(32, 16), 256, 0, stream>>>(attnb, WT, outf, 4096, 2048, 2048, DMODEL);
  } else {
    // Tier B (ws >= 50.33 MB): sliced QKV, attn in d_out, memcpy back.
    ushort* qkv   = (ushort*)ws;
    float*  of    = (float*)ws;
    ushort* wbT   = (ushort*)d_out + (size_t)4096 * 2048;
    ushort* attnb = xb;
    for (int s = 0; s < 3; s++) {
      cvt2dT<<<dim3(64, 64), dim3(32, 8), 0, stream>>>(Wqkvf + s * 2048, wbT, 2048, 2048, NQKV);
      gemm_bt<ushort><<<dim3(32, 16), 256, 0, stream>>>(xb, wbT, qkv + s * 2048, 4096, 2048, 2048, NQKV);
    }
    flash_attn<<<dim3(32, 32), 256, 0, stream>>>(qkv, attnb);
    cvt2dT<<<dim3(64, 64), dim3(32, 8), 0, stream>>>(Woutf, wbT, 2048, 2048, 2048);
    gemm_bt<float><<<dim3(32, 16), 256, 0, stream>>>(attnb, wbT, of, 4096, 2048, 2048, DMODEL);
    hipMemcpyAsync(outf, of, (size_t)4096 * 2048 * 4, hipMemcpyDeviceToDevice, stream);
  }
}

// Round 4
// 377.202 us; speedup vs baseline: 1.2012x; 1.2012x over previous
//
#include <hip/hip_runtime.h>

// Causal self-attention. fp32 in/out, bf16 MFMA compute inside.
// R11: QKV GEMM = BM=256 x BN=192 x BK=64(2x ks32), grid 16x32 = 512 blocks
// = exactly 2.0 balanced rounds at 1 block/CU (fixes R9's 1.5-round 25% idle
// WITHOUT R10's 48-frag register blowup: acc[8][3]=96 regs/wave, ~165 combined
// < 256 cap at 2 waves/EU). 2 phases/tile, 24 MFMA per barrier-pair (R9: 16).
// Double-buffered [2][2ks] LDS: sA 64KB + sB 48KB = 112KB, 1 block/CU.
// Stage schedule: tile t P0 stages {A,B}-ks1(t+1); P1 stages {A,B}-ks0(t+2);
// boundary vmcnt(3) (uniform-safe: waves0-3 issue 4 instr/pair, waves4-7 3).
// T2 swizzle unchanged from R9 (0 conflicts verified): granule g of row r at
// physical g^((r>>1)&3); LDS linear; global source pre-permuted; reads use
// quad^((l16>>1)&3). All row bases multiples of 16 -> formulas hold.
// Flash attn + out-GEMM (m97 128^2) unchanged.
// MFMA 16x16x32 bf16 layouts (guide m89/m91):
//   A[m=lane&15][k=quad*8+j], B[k=quad*8+j][n=lane&15], C/D: row=quad*4+r, col=lane&15

typedef unsigned short ushort;
typedef __attribute__((ext_vector_type(8))) short short8;
typedef __attribute__((ext_vector_type(4))) float floatx4;

#define T_SEQ 2048
#define NQKV  6144
#define DMODEL 2048
#define HDIM  128
#define NEG_BIG (-3.0e38f)

#define WAITVM(n) asm volatile("s_waitcnt vmcnt(" #n ")" ::: "memory")
#define WAITLGKM0 asm volatile("s_waitcnt lgkmcnt(0)" ::: "memory")

__device__ __forceinline__ ushort f2bf(float f) {
  unsigned u = __float_as_uint(f);
  u += 0x7fffu + ((u >> 16) & 1u);   // RNE
  return (ushort)(u >> 16);
}
__device__ __forceinline__ void stout(ushort* p, float v) { *p = f2bf(v); }
__device__ __forceinline__ void stout(float* p, float v)  { *p = v; }

__device__ __forceinline__ void gload_lds16(const ushort* g, ushort* l) {
  __builtin_amdgcn_global_load_lds(
      (const __attribute__((address_space(1))) void*)g,
      (__attribute__((address_space(3))) void*)l,
      16, 0, 0);
}

// ---- fp32 [R x C] (row stride ld_in) -> dense bf16 [R x C] ----
__global__ void cvt2d(const float* __restrict__ in, ushort* __restrict__ out,
                      int R, int C, int ld_in) {
  int idx = blockIdx.x * blockDim.x + threadIdx.x;
  int c4 = C >> 2;
  if (idx >= R * c4) return;
  int r = idx / c4, c = (idx - r * c4) * 4;
  float4 v = *(const float4*)(in + (size_t)r * ld_in + c);
  ushort4 o;
  o.x = f2bf(v.x); o.y = f2bf(v.y); o.z = f2bf(v.z); o.w = f2bf(v.w);
  *(ushort4*)(out + (size_t)r * C + c) = o;
}

// ---- fp32 in[R][C] (row stride ld_in) -> bf16 out[C][R] dense ----
__global__ void cvt2dT(const float* __restrict__ in, ushort* __restrict__ out,
                       int R, int C, int ld_in) {
  __shared__ float tile[32][33];
  int c0 = blockIdx.x * 32, r0 = blockIdx.y * 32;
  int tx = threadIdx.x, ty = threadIdx.y;  // 32 x 8
#pragma unroll
  for (int q = 0; q < 4; q++)
    tile[ty + q * 8][tx] = in[(size_t)(r0 + ty + q * 8) * ld_in + c0 + tx];
  __syncthreads();
#pragma unroll
  for (int q = 0; q < 4; q++)
    out[(size_t)(c0 + ty + q * 8) * R + r0 + tx] = f2bf(tile[tx][ty + q * 8]);
}

// ---- C[M,N] = A[M,K] @ Bt[N,K]^T, bf16 in, OutT out (m97 structure) ----
template <typename OutT>
__global__ void gemm_bt(
    const ushort* __restrict__ A, const ushort* __restrict__ Bt,
    OutT* __restrict__ C, int M, int N, int K, int ldc) {
  __shared__ ushort sA[128 * 32];
  __shared__ ushort sB[128 * 32];
  const int tid = threadIdx.x;
  const int w = tid >> 6, l = tid & 63;
  const int quad = l >> 4, l16 = l & 15;
  const int row0 = blockIdx.x * 128, col0 = blockIdx.y * 128;
  const int wm = (w >> 1) * 64, wn = (w & 1) * 64;

  floatx4 acc[4][4];
  const floatx4 zero = {0.f, 0.f, 0.f, 0.f};
#pragma unroll
  for (int i = 0; i < 4; i++)
#pragma unroll
    for (int j = 0; j < 4; j++) acc[i][j] = zero;

  const int srow = w * 16 + (l >> 2);
  const int scol = (l & 3) * 8;
  const ushort* gA = A + (size_t)(row0 + srow) * K + scol;
  const ushort* gB = Bt + (size_t)(col0 + srow) * K + scol;
  ushort* lA = &sA[(w * 16) * 32];
  ushort* lB = &sB[(w * 16) * 32];

  for (int k0 = 0; k0 < K; k0 += 32) {
    __syncthreads();
    gload_lds16(gA + k0, lA);
    gload_lds16(gA + k0 + (size_t)64 * K, lA + 64 * 32);
    gload_lds16(gB + k0, lB);
    gload_lds16(gB + k0 + (size_t)64 * K, lB + 64 * 32);
    __syncthreads();
    short8 af[4], bfr[4];
#pragma unroll
    for (int i = 0; i < 4; i++)
      af[i] = *(const short8*)&sA[(wm + i * 16 + l16) * 32 + quad * 8];
#pragma unroll
    for (int j = 0; j < 4; j++)
      bfr[j] = *(const short8*)&sB[(wn + j * 16 + l16) * 32 + quad * 8];
#pragma unroll
    for (int i = 0; i < 4; i++)
#pragma unroll
      for (int j = 0; j < 4; j++)
        acc[i][j] = __builtin_amdgcn_mfma_f32_16x16x32_bf16(af[i], bfr[j], acc[i][j], 0, 0, 0);
  }

#pragma unroll
  for (int i = 0; i < 4; i++)
#pragma unroll
    for (int j = 0; j < 4; j++) {
      int r0 = row0 + wm + i * 16 + quad * 4;
      int c = col0 + wn + j * 16 + l16;
#pragma unroll
      for (int r = 0; r < 4; r++)
        stout(&C[(size_t)(r0 + r) * ldc + c], acc[i][j][r]);
    }
}

// ---- QKV GEMM: C[M,N] = A[M,K] @ Bt[N,K]^T, BM=256 BN=192 BK=64 ----
// 512 threads = 8 waves (2M x 4N); per-wave C = 128x48 (8 m-frags x 3 n-frags,
// acc[8][3] = 96 VGPR). Grid 16x32 = 512 blocks = 2.0 exact rounds.
// LDS: sA[2][2][256*32] (64KB) + sB[2][2][192*32] (48KB) = 112KB, 1 block/CU.
// A staging: wave wid rows wid*32..+31 (2 instr). B staging: 12 chunks of 16
// rows; waves0-3 rows wid*32..+31 (2 instr), waves4-7 rows 128+(wid-4)*16 (1).
// Per tile t (buf=t&1), 2 phases: P0 (ks0, 24 MFMA) stages {A,B}-ks1(t+1);
// P1 (ks1, 24 MFMA) stages {A,B}-ks0(t+2); tail vmcnt(3) (t+2's pair in
// flight, everything tile t+1 needs at its P0 already landed).
template <typename OutT>
__global__ __launch_bounds__(512, 2) void gemm_qkv(
    const ushort* __restrict__ A, const ushort* __restrict__ Bt,
    OutT* __restrict__ C, int M, int N, int K, int ldc) {
  __shared__ ushort sA[2][2][256 * 32];
  __shared__ ushort sB[2][2][192 * 32];
  const int tid = threadIdx.x;
  const int wid = tid >> 6, l = tid & 63;
  const int quad = l >> 4, l16 = l & 15;
  const int wr = wid >> 2, wc = wid & 3;   // 2M x 4N
  const int row0 = blockIdx.x * 256, col0 = blockIdx.y * 192;
  const int NT = K >> 6;  // BK=64

  floatx4 acc[8][3];
  const floatx4 zero = {0.f, 0.f, 0.f, 0.f};
#pragma unroll
  for (int i = 0; i < 8; i++)
#pragma unroll
    for (int j = 0; j < 3; j++) acc[i][j] = zero;

  // stage source: lane l -> row chunkbase+(l>>2), granule (l&3)^((l>>3)&3)
  const int sgr = ((l & 3) ^ ((l >> 3) & 3)) * 8;
  const ushort* gA = A + (size_t)(row0 + wid * 32 + (l >> 2)) * K + sgr;
  const int brow0 = (wid < 4) ? wid * 32 : 128 + (wid - 4) * 16;
  const ushort* gB = Bt + (size_t)(col0 + brow0 + (l >> 2)) * K + sgr;

  auto stageA = [&](int tt, int ks) {   // 2 instr
    ushort* dst = &sA[tt & 1][ks][(wid * 32) * 32];
    const ushort* g = gA + tt * 64 + ks * 32;
    gload_lds16(g, dst);
    gload_lds16(g + (size_t)16 * K, dst + 16 * 32);
  };
  auto stageB = [&](int tt, int ks) {   // 2 instr (waves0-3) / 1 (waves4-7)
    ushort* dst = &sB[tt & 1][ks][brow0 * 32];
    const ushort* g = gB + tt * 64 + ks * 32;
    gload_lds16(g, dst);
    if (wid < 4) gload_lds16(g + (size_t)16 * K, dst + 16 * 32);
  };

  // read-side swizzled granule offset (frag row mod 16 == l16)
  const int gsw = (quad ^ ((l16 >> 1) & 3)) * 8;

  // prologue: stage t0 (both ks) + t1 ks0; vmcnt(3) -> t0 fully landed.
  stageA(0, 0); stageB(0, 0); stageA(0, 1); stageB(0, 1);
  if (NT > 1) {
    stageA(1, 0); stageB(1, 0);
    WAITVM(3);
  } else {
    WAITVM(0);
  }
  __builtin_amdgcn_s_barrier();

  for (int t = 0; t < NT; ++t) {
    const int b = t & 1;
    short8 af[8], bfr[3];
    // ---- P0 (ks=0): 24 MFMA ----
#pragma unroll
    for (int j = 0; j < 3; j++)
      bfr[j] = *(const short8*)&sB[b][0][(wc * 48 + j * 16 + l16) * 32 + gsw];
#pragma unroll
    for (int i = 0; i < 8; i++)
      af[i] = *(const short8*)&sA[b][0][(wr * 128 + i * 16 + l16) * 32 + gsw];
    if (t + 1 < NT) { stageA(t + 1, 1); stageB(t + 1, 1); }
    __builtin_amdgcn_s_barrier();
    WAITLGKM0;
    __builtin_amdgcn_s_setprio(1);
#pragma unroll
    for (int i = 0; i < 8; i++)
#pragma unroll
      for (int j = 0; j < 3; j++)
        acc[i][j] = __builtin_amdgcn_mfma_f32_16x16x32_bf16(af[i], bfr[j], acc[i][j], 0, 0, 0);
    __builtin_amdgcn_s_setprio(0);
    __builtin_amdgcn_s_barrier();
    // ---- P1 (ks=1): 24 MFMA ----
#pragma unroll
    for (int j = 0; j < 3; j++)
      bfr[j] = *(const short8*)&sB[b][1][(wc * 48 + j * 16 + l16) * 32 + gsw];
#pragma unroll
    for (int i = 0; i < 8; i++)
      af[i] = *(const short8*)&sA[b][1][(wr * 128 + i * 16 + l16) * 32 + gsw];
    if (t + 2 < NT) { stageA(t + 2, 0); stageB(t + 2, 0); }
    __builtin_amdgcn_s_barrier();
    WAITLGKM0;
    __builtin_amdgcn_s_setprio(1);
#pragma unroll
    for (int i = 0; i < 8; i++)
#pragma unroll
      for (int j = 0; j < 3; j++)
        acc[i][j] = __builtin_amdgcn_mfma_f32_16x16x32_bf16(af[i], bfr[j], acc[i][j], 0, 0, 0);
    __builtin_amdgcn_s_setprio(0);
    if (t < NT - 2) { WAITVM(3); } else { WAITVM(0); }
    __builtin_amdgcn_s_barrier();
  }

#pragma unroll
  for (int mi = 0; mi < 8; mi++)
#pragma unroll
    for (int j = 0; j < 3; j++) {
      int r0 = row0 + wr * 128 + mi * 16 + quad * 4;
      int c = col0 + wc * 48 + j * 16 + l16;
#pragma unroll
      for (int r = 0; r < 4; r++)
        stout(&C[(size_t)(r0 + r) * ldc + c], acc[mi][j][r]);
    }
}

// ---- flash attention (causal): one 64-row q-tile per block; grid (bh, qtOrd) ----
// sK: 2 buffers, 16 groups each; group = 4 rows x 128 ushort + 16-ushort pad
// (528 ushort stride). DMA writes one group per instruction (1024B contig);
// the pad staggers groups by 8 banks -> K-fragment b128 reads are 4-way.
__global__ __launch_bounds__(256, 2) void flash_attn(
    const ushort* __restrict__ qkv, ushort* __restrict__ attn) {
  __shared__ ushort sK[2][16 * 528];
  __shared__ ushort sVt[128 * 72];   // swizzled [hd][t]
  __shared__ ushort sP[4 * 16 * 72]; // per-wave P, stride 72

  const int tid = threadIdx.x;
  const int w = tid >> 6, l = tid & 63;
  const int quad = l >> 4, l16 = l & 15;
  const int bh = blockIdx.x;            // bh-major: same-bh blocks share an XCD
  const int qt = 31 - (int)blockIdx.y;  // biggest blocks dispatch first
  const int b = bh >> 4, h = bh & 15;
  const size_t rowbase = (size_t)b * T_SEQ;

  short8 qf[4];
  {
    const ushort* qp = qkv + (rowbase + qt * 64 + w * 16 + l16) * NQKV + h * HDIM + quad * 8;
#pragma unroll
    for (int s = 0; s < 4; s++) qf[s] = *(const short8*)(qp + s * 32);
  }
  floatx4 o[8];
  const floatx4 zero = {0.f, 0.f, 0.f, 0.f};
#pragma unroll
  for (int n = 0; n < 8; n++) o[n] = zero;
  float m_i[4], l_i[4];
#pragma unroll
  for (int r = 0; r < 4; r++) { m_i[r] = NEG_BIG; l_i[r] = 0.f; }

  // K DMA: instr c stages group w*4+c (rows w*16+c*4..+3);
  // lane l -> row +(l>>4), cols (l&15)*8..+7.
  const ushort* gK = qkv + (rowbase + w * 16 + (l >> 4)) * NQKV + 2048 + h * HDIM + (l & 15) * 8;
  auto issueK = [&](int kt, int buf) {
#pragma unroll
    for (int c = 0; c < 4; c++)
      gload_lds16(gK + (size_t)(kt * 64 + c * 4) * NQKV, &sK[buf][(w * 4 + c) * 528]);
  };
  // V: thread covers hd v_hd0..+7, t pair v_t0 (+32c)
  const int v_hd0 = (tid & 15) * 8;
  const int v_t0 = 2 * (tid >> 4);
  const ushort* gV = qkv + rowbase * NQKV + 4096 + h * HDIM + v_hd0;
  short8 vcur[4], vnxt[4];  // [0..1]=row t0 (c=0,1), [2..3]=row t0+1
  auto loadV = [&](int kt, short8* dst) {
#pragma unroll
    for (int c = 0; c < 2; c++) {
      const ushort* g = gV + (size_t)(kt * 64 + v_t0 + 32 * c) * NQKV;
      dst[c] = *(const short8*)g;
      dst[2 + c] = *(const short8*)(g + NQKV);
    }
  };

  ushort* myP = &sP[w * 16 * 72];
  const float scale = 0.08838834764831845f;  // 1/sqrt(128)

  auto attn_step = [&](bool diag, int buf) {
    floatx4 S[4];
#pragma unroll
    for (int j = 0; j < 4; j++) S[j] = zero;
#pragma unroll
    for (int s = 0; s < 4; s++)
#pragma unroll
      for (int j = 0; j < 4; j++) {
        int row = j * 16 + l16;
        short8 kf = *(const short8*)&sK[buf][(row >> 2) * 528 + (row & 3) * 128 + s * 32 + quad * 8];
        S[j] = __builtin_amdgcn_mfma_f32_16x16x32_bf16(qf[s], kf, S[j], 0, 0, 0);
      }
#pragma unroll
    for (int j = 0; j < 4; j++)
#pragma unroll
      for (int r = 0; r < 4; r++) {
        float v = S[j][r] * scale;
        if (diag && (j * 16 + l16 > w * 16 + quad * 4 + r)) v = NEG_BIG;
        S[j][r] = v;
      }
    float alpha[4];
#pragma unroll
    for (int r = 0; r < 4; r++) {
      float v = fmaxf(fmaxf(S[0][r], S[1][r]), fmaxf(S[2][r], S[3][r]));
      v = fmaxf(v, __shfl_xor(v, 1, 16));
      v = fmaxf(v, __shfl_xor(v, 2, 16));
      v = fmaxf(v, __shfl_xor(v, 4, 16));
      v = fmaxf(v, __shfl_xor(v, 8, 16));
      float mn = fmaxf(m_i[r], v);
      alpha[r] = __expf(m_i[r] - mn);
      m_i[r] = mn;
    }
#pragma unroll
    for (int j = 0; j < 4; j++)
#pragma unroll
      for (int r = 0; r < 4; r++) S[j][r] = __expf(S[j][r] - m_i[r]);
#pragma unroll
    for (int r = 0; r < 4; r++)
      l_i[r] = l_i[r] * alpha[r] + S[0][r] + S[1][r] + S[2][r] + S[3][r];
#pragma unroll
    for (int n = 0; n < 8; n++)
#pragma unroll
      for (int r = 0; r < 4; r++) o[n][r] *= alpha[r];
#pragma unroll
    for (int j = 0; j < 4; j++)
#pragma unroll
      for (int r = 0; r < 4; r++)
        myP[(quad * 4 + r) * 72 + j * 16 + l16] = f2bf(S[j][r]);
#pragma unroll
    for (int s = 0; s < 2; s++) {
      short8 pf = *(const short8*)&myP[l16 * 72 + s * 32 + quad * 8];
#pragma unroll
      for (int n = 0; n < 8; n++) {
        int hd = n * 16 + l16;
        short8 vf = *(const short8*)&sVt[hd * 72 + 8 * ((s * 4 + quad) ^ ((hd >> 3) & 7))];
        o[n] = __builtin_amdgcn_mfma_f32_16x16x32_bf16(pf, vf, o[n], 0, 0, 0);
      }
    }
  };

  issueK(0, 0);
  loadV(0, vcur);
  for (int kt = 0; kt <= qt; kt++) {
    const int buf = kt & 1;
    __syncthreads();   // drains this buf's K DMA (vmcnt0) + prev iter LDS reads
    // V^T staging (swizzled: write banks 2-way, reads b128 16B-aligned)
#pragma unroll
    for (int c = 0; c < 2; c++) {
      int tw = (v_t0 >> 1) + 16 * c;
#pragma unroll
      for (int j = 0; j < 8; j++) {
        int hd = v_hd0 + j;
        int phys = hd * 72 + 2 * (tw & 3) + 8 * ((tw >> 2) ^ ((hd >> 3) & 7));
        unsigned pv = ((unsigned)(ushort)vcur[c][j]) | (((unsigned)(ushort)vcur[2 + c][j]) << 16);
        *(unsigned*)&sVt[phys] = pv;
      }
    }
    __syncthreads();
    if (kt < qt) {     // prefetch next tile during this tile's compute
      issueK(kt + 1, buf ^ 1);
      loadV(kt + 1, vnxt);
    }
    attn_step(kt == qt, buf);
    if (kt < qt) {
#pragma unroll
      for (int c = 0; c < 4; c++) vcur[c] = vnxt[c];
    }
  }

  // epilogue: 1/l and store
#pragma unroll
  for (int r = 0; r < 4; r++) {
    float v = l_i[r];
    v += __shfl_xor(v, 1, 16);
    v += __shfl_xor(v, 2, 16);
    v += __shfl_xor(v, 4, 16);
    v += __shfl_xor(v, 8, 16);
    l_i[r] = 1.0f / v;
  }
#pragma unroll
  for (int n = 0; n < 8; n++) {
    int col = h * HDIM + n * 16 + l16;
#pragma unroll
    for (int r = 0; r < 4; r++) {
      int row = qt * 64 + w * 16 + quad * 4 + r;
      attn[(rowbase + row) * DMODEL + col] = f2bf(o[n][r] * l_i[r]);
    }
  }
}

extern "C" void kernel_launch(void* const* d_in, const int* in_sizes, int n_in,
                              void* d_out, int out_size, void* d_ws, size_t ws_size,
                              hipStream_t stream) {
  const float* xf    = (const float*)d_in[0];   // [4096, 2048] fp32
  const float* Wqkvf = (const float*)d_in[1];   // [2048, 6144] fp32
  const float* Woutf = (const float*)d_in[2];   // [2048, 2048] fp32
  float* outf = (float*)d_out;                  // [4096, 2048] fp32
  char* ws = (char*)d_ws;

  const size_t SZ_QKV  = (size_t)4096 * 6144 * 2;  // 50.33 MB
  const size_t SZ_ATTN = (size_t)4096 * 2048 * 2;  // 16.78 MB
  const size_t SZ_WQT  = (size_t)6144 * 2048 * 2;  // 25.17 MB

  ushort* xb = (ushort*)d_out;  // bf16 x in d_out scratch (dead before final write)
  cvt2d<<<8192, 256, 0, stream>>>(xf, xb, 4096, 2048, 2048);

  if (ws_size >= SZ_QKV + SZ_ATTN + SZ_WQT) {
    // Tier A: un-sliced QKV gemm (256x192, 512 blocks = 2.0 rounds), attn in
    // ws, final gemm direct to d_out.
    ushort* qkv   = (ushort*)ws;
    ushort* attnb = (ushort*)(ws + SZ_QKV);
    ushort* WT    = (ushort*)(ws + SZ_QKV + SZ_ATTN);
    cvt2dT<<<dim3(192, 64), dim3(32, 8), 0, stream>>>(Wqkvf, WT, 2048, 6144, NQKV);
    gemm_qkv<ushort><<<dim3(16, 32), 512, 0, stream>>>(xb, WT, qkv, 4096, 6144, 2048, NQKV);
    flash_attn<<<dim3(32, 32), 256, 0, stream>>>(qkv, attnb);
    cvt2dT<<<dim3(64, 64), dim3(32, 8), 0, stream>>>(Woutf, WT, 2048, 2048, 2048);
    gemm_bt<float><<<dim3(32, 16), 256, 0, stream>>>(attnb, WT, outf, 4096, 2048, 2048, DMODEL);
  } else {
    // Tier B (ws >= 50.33 MB): sliced QKV, attn in d_out, memcpy back.
    ushort* qkv   = (ushort*)ws;
    float*  of    = (float*)ws;
    ushort* wbT   = (ushort*)d_out + (size_t)4096 * 2048;
    ushort* attnb = xb;
    for (int s = 0; s < 3; s++) {
      cvt2dT<<<dim3(64, 64), dim3(32, 8), 0, stream>>>(Wqkvf + s * 2048, wbT, 2048, 2048, NQKV);
      gemm_bt<ushort><<<dim3(32, 16), 256, 0, stream>>>(xb, wbT, qkv + s * 2048, 4096, 2048, 2048, NQKV);
    }
    flash_attn<<<dim3(32, 32), 256, 0, stream>>>(qkv, attnb);
    cvt2dT<<<dim3(64, 64), dim3(32, 8), 0, stream>>>(Woutf, wbT, 2048, 2048, 2048);
    gemm_bt<float><<<dim3(32, 16), 256, 0, stream>>>(attnb, wbT, of, 4096, 2048, 2048, DMODEL);
    hipMemcpyAsync(outf, of, (size_t)4096 * 2048 * 4, hipMemcpyDeviceToDevice, stream);
  }
}

// Round 5
// 374.847 us; speedup vs baseline: 1.2088x; 1.0063x over previous
//
#include <hip/hip_runtime.h>

// Causal self-attention. fp32 in/out, bf16 MFMA compute inside.
// R12: (a) QKV GEMM wave-regrid 2Mx4N -> 4Mx2N (per-wave 64x96, acc[4][6],
// af[4]+bfr[6] = 10KB/ks reads vs 11): LDS-BW cap model (reads+DMA-writes vs
// MFMA cyc @256B/cyc/CU, validates m201=62%) rises 51%->55%.
// (b) out-projection ported from m97 gemm_bt to the same 2-phase counted-vmcnt
// template: BM=256 BN=128, grid 16x16 = 256 blocks = 1.0 round, 4Mx2N waves,
// acc[4][4], uniform 3 stage-instr/phase -> same vmcnt(3) schedule.
// QKV schedule/swizzle/staging unchanged from R11 (0 conflicts verified).
// Flash attn unchanged.
// MFMA 16x16x32 bf16 layouts (guide m89/m91):
//   A[m=lane&15][k=quad*8+j], B[k=quad*8+j][n=lane&15], C/D: row=quad*4+r, col=lane&15

typedef unsigned short ushort;
typedef __attribute__((ext_vector_type(8))) short short8;
typedef __attribute__((ext_vector_type(4))) float floatx4;

#define T_SEQ 2048
#define NQKV  6144
#define DMODEL 2048
#define HDIM  128
#define NEG_BIG (-3.0e38f)

#define WAITVM(n) asm volatile("s_waitcnt vmcnt(" #n ")" ::: "memory")
#define WAITLGKM0 asm volatile("s_waitcnt lgkmcnt(0)" ::: "memory")

__device__ __forceinline__ ushort f2bf(float f) {
  unsigned u = __float_as_uint(f);
  u += 0x7fffu + ((u >> 16) & 1u);   // RNE
  return (ushort)(u >> 16);
}
__device__ __forceinline__ void stout(ushort* p, float v) { *p = f2bf(v); }
__device__ __forceinline__ void stout(float* p, float v)  { *p = v; }

__device__ __forceinline__ void gload_lds16(const ushort* g, ushort* l) {
  __builtin_amdgcn_global_load_lds(
      (const __attribute__((address_space(1))) void*)g,
      (__attribute__((address_space(3))) void*)l,
      16, 0, 0);
}

// ---- fp32 [R x C] (row stride ld_in) -> dense bf16 [R x C] ----
__global__ void cvt2d(const float* __restrict__ in, ushort* __restrict__ out,
                      int R, int C, int ld_in) {
  int idx = blockIdx.x * blockDim.x + threadIdx.x;
  int c4 = C >> 2;
  if (idx >= R * c4) return;
  int r = idx / c4, c = (idx - r * c4) * 4;
  float4 v = *(const float4*)(in + (size_t)r * ld_in + c);
  ushort4 o;
  o.x = f2bf(v.x); o.y = f2bf(v.y); o.z = f2bf(v.z); o.w = f2bf(v.w);
  *(ushort4*)(out + (size_t)r * C + c) = o;
}

// ---- fp32 in[R][C] (row stride ld_in) -> bf16 out[C][R] dense ----
__global__ void cvt2dT(const float* __restrict__ in, ushort* __restrict__ out,
                       int R, int C, int ld_in) {
  __shared__ float tile[32][33];
  int c0 = blockIdx.x * 32, r0 = blockIdx.y * 32;
  int tx = threadIdx.x, ty = threadIdx.y;  // 32 x 8
#pragma unroll
  for (int q = 0; q < 4; q++)
    tile[ty + q * 8][tx] = in[(size_t)(r0 + ty + q * 8) * ld_in + c0 + tx];
  __syncthreads();
#pragma unroll
  for (int q = 0; q < 4; q++)
    out[(size_t)(c0 + ty + q * 8) * R + r0 + tx] = f2bf(tile[tx][ty + q * 8]);
}

// ---- C[M,N] = A[M,K] @ Bt[N,K]^T, bf16 in, OutT out (m97 structure) ----
template <typename OutT>
__global__ void gemm_bt(
    const ushort* __restrict__ A, const ushort* __restrict__ Bt,
    OutT* __restrict__ C, int M, int N, int K, int ldc) {
  __shared__ ushort sA[128 * 32];
  __shared__ ushort sB[128 * 32];
  const int tid = threadIdx.x;
  const int w = tid >> 6, l = tid & 63;
  const int quad = l >> 4, l16 = l & 15;
  const int row0 = blockIdx.x * 128, col0 = blockIdx.y * 128;
  const int wm = (w >> 1) * 64, wn = (w & 1) * 64;

  floatx4 acc[4][4];
  const floatx4 zero = {0.f, 0.f, 0.f, 0.f};
#pragma unroll
  for (int i = 0; i < 4; i++)
#pragma unroll
    for (int j = 0; j < 4; j++) acc[i][j] = zero;

  const int srow = w * 16 + (l >> 2);
  const int scol = (l & 3) * 8;
  const ushort* gA = A + (size_t)(row0 + srow) * K + scol;
  const ushort* gB = Bt + (size_t)(col0 + srow) * K + scol;
  ushort* lA = &sA[(w * 16) * 32];
  ushort* lB = &sB[(w * 16) * 32];

  for (int k0 = 0; k0 < K; k0 += 32) {
    __syncthreads();
    gload_lds16(gA + k0, lA);
    gload_lds16(gA + k0 + (size_t)64 * K, lA + 64 * 32);
    gload_lds16(gB + k0, lB);
    gload_lds16(gB + k0 + (size_t)64 * K, lB + 64 * 32);
    __syncthreads();
    short8 af[4], bfr[4];
#pragma unroll
    for (int i = 0; i < 4; i++)
      af[i] = *(const short8*)&sA[(wm + i * 16 + l16) * 32 + quad * 8];
#pragma unroll
    for (int j = 0; j < 4; j++)
      bfr[j] = *(const short8*)&sB[(wn + j * 16 + l16) * 32 + quad * 8];
#pragma unroll
    for (int i = 0; i < 4; i++)
#pragma unroll
      for (int j = 0; j < 4; j++)
        acc[i][j] = __builtin_amdgcn_mfma_f32_16x16x32_bf16(af[i], bfr[j], acc[i][j], 0, 0, 0);
  }

#pragma unroll
  for (int i = 0; i < 4; i++)
#pragma unroll
    for (int j = 0; j < 4; j++) {
      int r0 = row0 + wm + i * 16 + quad * 4;
      int c = col0 + wn + j * 16 + l16;
#pragma unroll
      for (int r = 0; r < 4; r++)
        stout(&C[(size_t)(r0 + r) * ldc + c], acc[i][j][r]);
    }
}

// ---- QKV GEMM: C[M,N] = A[M,K] @ Bt[N,K]^T, BM=256 BN=192 BK=64 ----
// 512 threads = 8 waves, 4M x 2N: per-wave C = 64x96 (4 m-frags x 6 n-frags,
// acc[4][6] = 96 VGPR; reads af[4]+bfr[6] = 10KB/ks, was 11 at 2Mx4N).
// Grid 16x32 = 512 blocks = 2.0 exact rounds.
// LDS: sA[2][2][256*32] (64KB) + sB[2][2][192*32] (48KB) = 112KB, 1 block/CU.
// A staging: wave wid rows wid*32..+31 (2 instr). B staging: 12 chunks of 16
// rows; waves0-3 rows wid*32..+31 (2 instr), waves4-7 rows 128+(wid-4)*16 (1).
// Per tile t (buf=t&1), 2 phases: P0 (ks0, 24 MFMA) stages {A,B}-ks1(t+1);
// P1 (ks1, 24 MFMA) stages {A,B}-ks0(t+2); tail vmcnt(3).
// T2 swizzle (0 conflicts verified R9): granule g of row r at physical
// g^((r>>1)&3); LDS linear; global source pre-permuted; reads quad^((l16>>1)&3).
template <typename OutT>
__global__ __launch_bounds__(512, 2) void gemm_qkv(
    const ushort* __restrict__ A, const ushort* __restrict__ Bt,
    OutT* __restrict__ C, int M, int N, int K, int ldc) {
  __shared__ ushort sA[2][2][256 * 32];
  __shared__ ushort sB[2][2][192 * 32];
  const int tid = threadIdx.x;
  const int wid = tid >> 6, l = tid & 63;
  const int quad = l >> 4, l16 = l & 15;
  const int wr = wid & 3, wc = wid >> 2;   // 4M x 2N
  const int row0 = blockIdx.x * 256, col0 = blockIdx.y * 192;
  const int NT = K >> 6;  // BK=64

  floatx4 acc[4][6];
  const floatx4 zero = {0.f, 0.f, 0.f, 0.f};
#pragma unroll
  for (int i = 0; i < 4; i++)
#pragma unroll
    for (int j = 0; j < 6; j++) acc[i][j] = zero;

  // stage source: lane l -> row chunkbase+(l>>2), granule (l&3)^((l>>3)&3)
  const int sgr = ((l & 3) ^ ((l >> 3) & 3)) * 8;
  const ushort* gA = A + (size_t)(row0 + wid * 32 + (l >> 2)) * K + sgr;
  const int brow0 = (wid < 4) ? wid * 32 : 128 + (wid - 4) * 16;
  const ushort* gB = Bt + (size_t)(col0 + brow0 + (l >> 2)) * K + sgr;

  auto stageA = [&](int tt, int ks) {   // 2 instr
    ushort* dst = &sA[tt & 1][ks][(wid * 32) * 32];
    const ushort* g = gA + tt * 64 + ks * 32;
    gload_lds16(g, dst);
    gload_lds16(g + (size_t)16 * K, dst + 16 * 32);
  };
  auto stageB = [&](int tt, int ks) {   // 2 instr (waves0-3) / 1 (waves4-7)
    ushort* dst = &sB[tt & 1][ks][brow0 * 32];
    const ushort* g = gB + tt * 64 + ks * 32;
    gload_lds16(g, dst);
    if (wid < 4) gload_lds16(g + (size_t)16 * K, dst + 16 * 32);
  };

  // read-side swizzled granule offset (frag row mod 16 == l16)
  const int gsw = (quad ^ ((l16 >> 1) & 3)) * 8;

  // prologue: stage t0 (both ks) + t1 ks0; vmcnt(3) -> t0 fully landed.
  stageA(0, 0); stageB(0, 0); stageA(0, 1); stageB(0, 1);
  if (NT > 1) {
    stageA(1, 0); stageB(1, 0);
    WAITVM(3);
  } else {
    WAITVM(0);
  }
  __builtin_amdgcn_s_barrier();

  for (int t = 0; t < NT; ++t) {
    const int b = t & 1;
    short8 af[4], bfr[6];
    // ---- P0 (ks=0): 24 MFMA ----
#pragma unroll
    for (int j = 0; j < 6; j++)
      bfr[j] = *(const short8*)&sB[b][0][(wc * 96 + j * 16 + l16) * 32 + gsw];
#pragma unroll
    for (int i = 0; i < 4; i++)
      af[i] = *(const short8*)&sA[b][0][(wr * 64 + i * 16 + l16) * 32 + gsw];
    if (t + 1 < NT) { stageA(t + 1, 1); stageB(t + 1, 1); }
    __builtin_amdgcn_s_barrier();
    WAITLGKM0;
    __builtin_amdgcn_s_setprio(1);
#pragma unroll
    for (int i = 0; i < 4; i++)
#pragma unroll
      for (int j = 0; j < 6; j++)
        acc[i][j] = __builtin_amdgcn_mfma_f32_16x16x32_bf16(af[i], bfr[j], acc[i][j], 0, 0, 0);
    __builtin_amdgcn_s_setprio(0);
    __builtin_amdgcn_s_barrier();
    // ---- P1 (ks=1): 24 MFMA ----
#pragma unroll
    for (int j = 0; j < 6; j++)
      bfr[j] = *(const short8*)&sB[b][1][(wc * 96 + j * 16 + l16) * 32 + gsw];
#pragma unroll
    for (int i = 0; i < 4; i++)
      af[i] = *(const short8*)&sA[b][1][(wr * 64 + i * 16 + l16) * 32 + gsw];
    if (t + 2 < NT) { stageA(t + 2, 0); stageB(t + 2, 0); }
    __builtin_amdgcn_s_barrier();
    WAITLGKM0;
    __builtin_amdgcn_s_setprio(1);
#pragma unroll
    for (int i = 0; i < 4; i++)
#pragma unroll
      for (int j = 0; j < 6; j++)
        acc[i][j] = __builtin_amdgcn_mfma_f32_16x16x32_bf16(af[i], bfr[j], acc[i][j], 0, 0, 0);
    __builtin_amdgcn_s_setprio(0);
    if (t < NT - 2) { WAITVM(3); } else { WAITVM(0); }
    __builtin_amdgcn_s_barrier();
  }

#pragma unroll
  for (int mi = 0; mi < 4; mi++)
#pragma unroll
    for (int j = 0; j < 6; j++) {
      int r0 = row0 + wr * 64 + mi * 16 + quad * 4;
      int c = col0 + wc * 96 + j * 16 + l16;
#pragma unroll
      for (int r = 0; r < 4; r++)
        stout(&C[(size_t)(r0 + r) * ldc + c], acc[mi][j][r]);
    }
}

// ---- OUT GEMM: C[M,N] = A[M,K] @ Bt[N,K]^T, BM=256 BN=128 BK=64 ----
// Same template as gemm_qkv: 8 waves 4M x 2N, per-wave C = 64x64 (acc[4][4]).
// Grid 16x16 = 256 blocks = 1.0 round. LDS: sA 64KB + sB 32KB = 96KB.
// Staging: A wave wid rows wid*32 (2 instr); B wave wid rows wid*16 (1 instr)
// -> uniform 3 instr/phase, same vmcnt(3) schedule as gemm_qkv.
template <typename OutT>
__global__ __launch_bounds__(512, 2) void gemm_out(
    const ushort* __restrict__ A, const ushort* __restrict__ Bt,
    OutT* __restrict__ C, int M, int N, int K, int ldc) {
  __shared__ ushort sA[2][2][256 * 32];
  __shared__ ushort sB[2][2][128 * 32];
  const int tid = threadIdx.x;
  const int wid = tid >> 6, l = tid & 63;
  const int quad = l >> 4, l16 = l & 15;
  const int wr = wid & 3, wc = wid >> 2;   // 4M x 2N
  const int row0 = blockIdx.x * 256, col0 = blockIdx.y * 128;
  const int NT = K >> 6;  // BK=64

  floatx4 acc[4][4];
  const floatx4 zero = {0.f, 0.f, 0.f, 0.f};
#pragma unroll
  for (int i = 0; i < 4; i++)
#pragma unroll
    for (int j = 0; j < 4; j++) acc[i][j] = zero;

  const int sgr = ((l & 3) ^ ((l >> 3) & 3)) * 8;
  const ushort* gA = A + (size_t)(row0 + wid * 32 + (l >> 2)) * K + sgr;
  const ushort* gB = Bt + (size_t)(col0 + wid * 16 + (l >> 2)) * K + sgr;

  auto stageA = [&](int tt, int ks) {   // 2 instr
    ushort* dst = &sA[tt & 1][ks][(wid * 32) * 32];
    const ushort* g = gA + tt * 64 + ks * 32;
    gload_lds16(g, dst);
    gload_lds16(g + (size_t)16 * K, dst + 16 * 32);
  };
  auto stageB = [&](int tt, int ks) {   // 1 instr
    gload_lds16(gB + tt * 64 + ks * 32, &sB[tt & 1][ks][(wid * 16) * 32]);
  };

  const int gsw = (quad ^ ((l16 >> 1) & 3)) * 8;

  stageA(0, 0); stageB(0, 0); stageA(0, 1); stageB(0, 1);
  if (NT > 1) {
    stageA(1, 0); stageB(1, 0);
    WAITVM(3);
  } else {
    WAITVM(0);
  }
  __builtin_amdgcn_s_barrier();

  for (int t = 0; t < NT; ++t) {
    const int b = t & 1;
    short8 af[4], bfr[4];
    // ---- P0 (ks=0): 16 MFMA ----
#pragma unroll
    for (int j = 0; j < 4; j++)
      bfr[j] = *(const short8*)&sB[b][0][(wc * 64 + j * 16 + l16) * 32 + gsw];
#pragma unroll
    for (int i = 0; i < 4; i++)
      af[i] = *(const short8*)&sA[b][0][(wr * 64 + i * 16 + l16) * 32 + gsw];
    if (t + 1 < NT) { stageA(t + 1, 1); stageB(t + 1, 1); }
    __builtin_amdgcn_s_barrier();
    WAITLGKM0;
    __builtin_amdgcn_s_setprio(1);
#pragma unroll
    for (int i = 0; i < 4; i++)
#pragma unroll
      for (int j = 0; j < 4; j++)
        acc[i][j] = __builtin_amdgcn_mfma_f32_16x16x32_bf16(af[i], bfr[j], acc[i][j], 0, 0, 0);
    __builtin_amdgcn_s_setprio(0);
    __builtin_amdgcn_s_barrier();
    // ---- P1 (ks=1): 16 MFMA ----
#pragma unroll
    for (int j = 0; j < 4; j++)
      bfr[j] = *(const short8*)&sB[b][1][(wc * 64 + j * 16 + l16) * 32 + gsw];
#pragma unroll
    for (int i = 0; i < 4; i++)
      af[i] = *(const short8*)&sA[b][1][(wr * 64 + i * 16 + l16) * 32 + gsw];
    if (t + 2 < NT) { stageA(t + 2, 0); stageB(t + 2, 0); }
    __builtin_amdgcn_s_barrier();
    WAITLGKM0;
    __builtin_amdgcn_s_setprio(1);
#pragma unroll
    for (int i = 0; i < 4; i++)
#pragma unroll
      for (int j = 0; j < 4; j++)
        acc[i][j] = __builtin_amdgcn_mfma_f32_16x16x32_bf16(af[i], bfr[j], acc[i][j], 0, 0, 0);
    __builtin_amdgcn_s_setprio(0);
    if (t < NT - 2) { WAITVM(3); } else { WAITVM(0); }
    __builtin_amdgcn_s_barrier();
  }

#pragma unroll
  for (int mi = 0; mi < 4; mi++)
#pragma unroll
    for (int j = 0; j < 4; j++) {
      int r0 = row0 + wr * 64 + mi * 16 + quad * 4;
      int c = col0 + wc * 64 + j * 16 + l16;
#pragma unroll
      for (int r = 0; r < 4; r++)
        stout(&C[(size_t)(r0 + r) * ldc + c], acc[mi][j][r]);
    }
}

// ---- flash attention (causal): one 64-row q-tile per block; grid (bh, qtOrd) ----
// sK: 2 buffers, 16 groups each; group = 4 rows x 128 ushort + 16-ushort pad
// (528 ushort stride). DMA writes one group per instruction (1024B contig);
// the pad staggers groups by 8 banks -> K-fragment b128 reads are 4-way.
__global__ __launch_bounds__(256, 2) void flash_attn(
    const ushort* __restrict__ qkv, ushort* __restrict__ attn) {
  __shared__ ushort sK[2][16 * 528];
  __shared__ ushort sVt[128 * 72];   // swizzled [hd][t]
  __shared__ ushort sP[4 * 16 * 72]; // per-wave P, stride 72

  const int tid = threadIdx.x;
  const int w = tid >> 6, l = tid & 63;
  const int quad = l >> 4, l16 = l & 15;
  const int bh = blockIdx.x;            // bh-major: same-bh blocks share an XCD
  const int qt = 31 - (int)blockIdx.y;  // biggest blocks dispatch first
  const int b = bh >> 4, h = bh & 15;
  const size_t rowbase = (size_t)b * T_SEQ;

  short8 qf[4];
  {
    const ushort* qp = qkv + (rowbase + qt * 64 + w * 16 + l16) * NQKV + h * HDIM + quad * 8;
#pragma unroll
    for (int s = 0; s < 4; s++) qf[s] = *(const short8*)(qp + s * 32);
  }
  floatx4 o[8];
  const floatx4 zero = {0.f, 0.f, 0.f, 0.f};
#pragma unroll
  for (int n = 0; n < 8; n++) o[n] = zero;
  float m_i[4], l_i[4];
#pragma unroll
  for (int r = 0; r < 4; r++) { m_i[r] = NEG_BIG; l_i[r] = 0.f; }

  // K DMA: instr c stages group w*4+c (rows w*16+c*4..+3);
  // lane l -> row +(l>>4), cols (l&15)*8..+7.
  const ushort* gK = qkv + (rowbase + w * 16 + (l >> 4)) * NQKV + 2048 + h * HDIM + (l & 15) * 8;
  auto issueK = [&](int kt, int buf) {
#pragma unroll
    for (int c = 0; c < 4; c++)
      gload_lds16(gK + (size_t)(kt * 64 + c * 4) * NQKV, &sK[buf][(w * 4 + c) * 528]);
  };
  // V: thread covers hd v_hd0..+7, t pair v_t0 (+32c)
  const int v_hd0 = (tid & 15) * 8;
  const int v_t0 = 2 * (tid >> 4);
  const ushort* gV = qkv + rowbase * NQKV + 4096 + h * HDIM + v_hd0;
  short8 vcur[4], vnxt[4];  // [0..1]=row t0 (c=0,1), [2..3]=row t0+1
  auto loadV = [&](int kt, short8* dst) {
#pragma unroll
    for (int c = 0; c < 2; c++) {
      const ushort* g = gV + (size_t)(kt * 64 + v_t0 + 32 * c) * NQKV;
      dst[c] = *(const short8*)g;
      dst[2 + c] = *(const short8*)(g + NQKV);
    }
  };

  ushort* myP = &sP[w * 16 * 72];
  const float scale = 0.08838834764831845f;  // 1/sqrt(128)

  auto attn_step = [&](bool diag, int buf) {
    floatx4 S[4];
#pragma unroll
    for (int j = 0; j < 4; j++) S[j] = zero;
#pragma unroll
    for (int s = 0; s < 4; s++)
#pragma unroll
      for (int j = 0; j < 4; j++) {
        int row = j * 16 + l16;
        short8 kf = *(const short8*)&sK[buf][(row >> 2) * 528 + (row & 3) * 128 + s * 32 + quad * 8];
        S[j] = __builtin_amdgcn_mfma_f32_16x16x32_bf16(qf[s], kf, S[j], 0, 0, 0);
      }
#pragma unroll
    for (int j = 0; j < 4; j++)
#pragma unroll
      for (int r = 0; r < 4; r++) {
        float v = S[j][r] * scale;
        if (diag && (j * 16 + l16 > w * 16 + quad * 4 + r)) v = NEG_BIG;
        S[j][r] = v;
      }
    float alpha[4];
#pragma unroll
    for (int r = 0; r < 4; r++) {
      float v = fmaxf(fmaxf(S[0][r], S[1][r]), fmaxf(S[2][r], S[3][r]));
      v = fmaxf(v, __shfl_xor(v, 1, 16));
      v = fmaxf(v, __shfl_xor(v, 2, 16));
      v = fmaxf(v, __shfl_xor(v, 4, 16));
      v = fmaxf(v, __shfl_xor(v, 8, 16));
      float mn = fmaxf(m_i[r], v);
      alpha[r] = __expf(m_i[r] - mn);
      m_i[r] = mn;
    }
#pragma unroll
    for (int j = 0; j < 4; j++)
#pragma unroll
      for (int r = 0; r < 4; r++) S[j][r] = __expf(S[j][r] - m_i[r]);
#pragma unroll
    for (int r = 0; r < 4; r++)
      l_i[r] = l_i[r] * alpha[r] + S[0][r] + S[1][r] + S[2][r] + S[3][r];
#pragma unroll
    for (int n = 0; n < 8; n++)
#pragma unroll
      for (int r = 0; r < 4; r++) o[n][r] *= alpha[r];
#pragma unroll
    for (int j = 0; j < 4; j++)
#pragma unroll
      for (int r = 0; r < 4; r++)
        myP[(quad * 4 + r) * 72 + j * 16 + l16] = f2bf(S[j][r]);
#pragma unroll
    for (int s = 0; s < 2; s++) {
      short8 pf = *(const short8*)&myP[l16 * 72 + s * 32 + quad * 8];
#pragma unroll
      for (int n = 0; n < 8; n++) {
        int hd = n * 16 + l16;
        short8 vf = *(const short8*)&sVt[hd * 72 + 8 * ((s * 4 + quad) ^ ((hd >> 3) & 7))];
        o[n] = __builtin_amdgcn_mfma_f32_16x16x32_bf16(pf, vf, o[n], 0, 0, 0);
      }
    }
  };

  issueK(0, 0);
  loadV(0, vcur);
  for (int kt = 0; kt <= qt; kt++) {
    const int buf = kt & 1;
    __syncthreads();   // drains this buf's K DMA (vmcnt0) + prev iter LDS reads
    // V^T staging (swizzled: write banks 2-way, reads b128 16B-aligned)
#pragma unroll
    for (int c = 0; c < 2; c++) {
      int tw = (v_t0 >> 1) + 16 * c;
#pragma unroll
      for (int j = 0; j < 8; j++) {
        int hd = v_hd0 + j;
        int phys = hd * 72 + 2 * (tw & 3) + 8 * ((tw >> 2) ^ ((hd >> 3) & 7));
        unsigned pv = ((unsigned)(ushort)vcur[c][j]) | (((unsigned)(ushort)vcur[2 + c][j]) << 16);
        *(unsigned*)&sVt[phys] = pv;
      }
    }
    __syncthreads();
    if (kt < qt) {     // prefetch next tile during this tile's compute
      issueK(kt + 1, buf ^ 1);
      loadV(kt + 1, vnxt);
    }
    attn_step(kt == qt, buf);
    if (kt < qt) {
#pragma unroll
      for (int c = 0; c < 4; c++) vcur[c] = vnxt[c];
    }
  }

  // epilogue: 1/l and store
#pragma unroll
  for (int r = 0; r < 4; r++) {
    float v = l_i[r];
    v += __shfl_xor(v, 1, 16);
    v += __shfl_xor(v, 2, 16);
    v += __shfl_xor(v, 4, 16);
    v += __shfl_xor(v, 8, 16);
    l_i[r] = 1.0f / v;
  }
#pragma unroll
  for (int n = 0; n < 8; n++) {
    int col = h * HDIM + n * 16 + l16;
#pragma unroll
    for (int r = 0; r < 4; r++) {
      int row = qt * 64 + w * 16 + quad * 4 + r;
      attn[(rowbase + row) * DMODEL + col] = f2bf(o[n][r] * l_i[r]);
    }
  }
}

extern "C" void kernel_launch(void* const* d_in, const int* in_sizes, int n_in,
                              void* d_out, int out_size, void* d_ws, size_t ws_size,
                              hipStream_t stream) {
  const float* xf    = (const float*)d_in[0];   // [4096, 2048] fp32
  const float* Wqkvf = (const float*)d_in[1];   // [2048, 6144] fp32
  const float* Woutf = (const float*)d_in[2];   // [2048, 2048] fp32
  float* outf = (float*)d_out;                  // [4096, 2048] fp32
  char* ws = (char*)d_ws;

  const size_t SZ_QKV  = (size_t)4096 * 6144 * 2;  // 50.33 MB
  const size_t SZ_ATTN = (size_t)4096 * 2048 * 2;  // 16.78 MB
  const size_t SZ_WQT  = (size_t)6144 * 2048 * 2;  // 25.17 MB

  ushort* xb = (ushort*)d_out;  // bf16 x in d_out scratch (dead before final write)
  cvt2d<<<8192, 256, 0, stream>>>(xf, xb, 4096, 2048, 2048);

  if (ws_size >= SZ_QKV + SZ_ATTN + SZ_WQT) {
    // Tier A: un-sliced QKV gemm (256x192, 512 blocks = 2.0 rounds), attn in
    // ws, out-proj (256x128, 256 blocks = 1.0 round) direct to d_out.
    ushort* qkv   = (ushort*)ws;
    ushort* attnb = (ushort*)(ws + SZ_QKV);
    ushort* WT    = (ushort*)(ws + SZ_QKV + SZ_ATTN);
    cvt2dT<<<dim3(192, 64), dim3(32, 8), 0, stream>>>(Wqkvf, WT, 2048, 6144, NQKV);
    gemm_qkv<ushort><<<dim3(16, 32), 512, 0, stream>>>(xb, WT, qkv, 4096, 6144, 2048, NQKV);
    flash_attn<<<dim3(32, 32), 256, 0, stream>>>(qkv, attnb);
    cvt2dT<<<dim3(64, 64), dim3(32, 8), 0, stream>>>(Woutf, WT, 2048, 2048, 2048);
    gemm_out<float><<<dim3(16, 16), 512, 0, stream>>>(attnb, WT, outf, 4096, 2048, 2048, DMODEL);
  } else {
    // Tier B (ws >= 50.33 MB): sliced QKV, attn in d_out, memcpy back.
    ushort* qkv   = (ushort*)ws;
    float*  of    = (float*)ws;
    ushort* wbT   = (ushort*)d_out + (size_t)4096 * 2048;
    ushort* attnb = xb;
    for (int s = 0; s < 3; s++) {
      cvt2dT<<<dim3(64, 64), dim3(32, 8), 0, stream>>>(Wqkvf + s * 2048, wbT, 2048, 2048, NQKV);
      gemm_bt<ushort><<<dim3(32, 16), 256, 0, stream>>>(xb, wbT, qkv + s * 2048, 4096, 2048, 2048, NQKV);
    }
    flash_attn<<<dim3(32, 32), 256, 0, stream>>>(qkv, attnb);
    cvt2dT<<<dim3(64, 64), dim3(32, 8), 0, stream>>>(Woutf, wbT, 2048, 2048, 2048);
    gemm_bt<float><<<dim3(32, 16), 256, 0, stream>>>(attnb, wbT, of, 4096, 2048, 2048, DMODEL);
    hipMemcpyAsync(outf, of, (size_t)4096 * 2048 * 4, hipMemcpyDeviceToDevice, stream);
  }
}